// Round 5
// baseline (472.580 us; speedup 1.0000x reference)
//
#include <hip/hip_runtime.h>
#include <stdint.h>

typedef __bf16 bf16_t;
typedef __bf16 bf16x8 __attribute__((ext_vector_type(8)));
typedef float floatx4 __attribute__((ext_vector_type(4)));

#define B_ 8
#define N_ 2048
#define D_ 768
#define H_ 64

// R5 = INSTRUMENTATION ROUND: proj/attn grids duplicated x8 (idempotent,
// byte-identical concurrent stores) so each dispatch exceeds the 43us fill
// cutoff and surfaces in rocprof top-5 with real counters.  dur/8 = per-run
// cost.  Kernel bodies are bit-identical to R4.
#define PROJ_DUP 8
#define ATTN_DUP 8

__device__ __forceinline__ bf16_t f2bf(float f) {
    union { float f; uint32_t u; } v; v.f = f;
    uint32_t u = v.u;
    uint32_t r = (u + 0x7fffu + ((u >> 16) & 1u)) >> 16;
    union { unsigned short s; bf16_t b; } o; o.s = (unsigned short)r;
    return o.b;
}

__device__ __forceinline__ void async_cp16(void* l, const void* g) {
    __builtin_amdgcn_global_load_lds(
        (const __attribute__((address_space(1))) uint32_t*)g,
        (__attribute__((address_space(3))) uint32_t*)l, 16, 0, 0);
}

// ---------------------------------------------------------------------------
// Kernel 1: W transpose + cast (unchanged).
// ---------------------------------------------------------------------------
__global__ void wt_kernel(const float* __restrict__ Wq,
                          const float* __restrict__ Wk,
                          const float* __restrict__ Wv,
                          bf16_t* __restrict__ Wt) {
    const int h = threadIdx.x;
    const int k = blockIdx.x;
    const int s = blockIdx.y;
    const float* W = (s == 0) ? Wq : (s == 1) ? Wk : Wv;
    float v = W[k * H_ + h];
    if (s == 0) v *= 0.125f * 1.4426950408889634f;
    Wt[(size_t)(s * 64 + h) * D_ + k] = f2bf(v);
}

// ---------------------------------------------------------------------------
// Kernel 2: fused QKV projection (R4 body; blockIdx.x masked for dup).
// ---------------------------------------------------------------------------
__launch_bounds__(256, 2)
__global__ void proj_kernel(const float* __restrict__ X,
                            const bf16_t* __restrict__ Wt,
                            bf16_t* __restrict__ Qb,
                            bf16_t* __restrict__ Kb,
                            bf16_t* __restrict__ Vt) {
    const int wave = threadIdx.x >> 6;
    const int lane = threadIdx.x & 63;
    const int quad = lane >> 4;
    const int l16  = lane & 15;
    const int rowhalf = wave & 1;
    const int colhalf = wave >> 1;
    const int m0blk = (blockIdx.x & 511) * 32;   // dup copies alias the tile

    __shared__ __align__(16) float  As[2][32 * 64];
    __shared__ __align__(16) bf16_t Bs[2][192 * 64];

    floatx4 acc[6];
#pragma unroll
    for (int i = 0; i < 6; i++) acc[i] = (floatx4){0.f, 0.f, 0.f, 0.f};

    auto stage = [&](int buf, int k0) {
#pragma unroll
        for (int i = 0; i < 2; i++) {
            const int r = (wave * 2 + i) * 4 + (lane >> 4);
            const int c = (lane & 15) ^ (r & 15);
            const float* g = X + (size_t)(m0blk + r) * D_ + k0 + c * 4;
            async_cp16((char*)&As[buf][0] + (wave * 2 + i) * 1024, g);
        }
#pragma unroll
        for (int i = 0; i < 6; i++) {
            const int r = (wave * 6 + i) * 8 + (lane >> 3);
            const int c = (lane & 7) ^ (r & 7);
            const bf16_t* g = Wt + (size_t)r * D_ + k0 + c * 8;
            async_cp16((char*)&Bs[buf][0] + (wave * 6 + i) * 1024, g);
        }
    };

    const int arow = rowhalf * 16 + l16;

    stage(0, 0);
    for (int ch = 0; ch < 12; ch++) {
        __syncthreads();
        if (ch + 1 < 12) stage((ch + 1) & 1, (ch + 1) * 64);

        const char* Ab = (const char*)&As[ch & 1][0];
        const char* Bb = (const char*)&Bs[ch & 1][0];
#pragma unroll
        for (int kh = 0; kh < 2; kh++) {
            const int c0 = kh * 8 + quad * 2;
            float4 xa = *(const float4*)(Ab + arow * 256 + ((c0 ^ l16) & 15) * 16);
            float4 xb = *(const float4*)(Ab + arow * 256 + (((c0 + 1) ^ l16) & 15) * 16);
            bf16x8 af;
            af[0] = f2bf(xa.x); af[1] = f2bf(xa.y);
            af[2] = f2bf(xa.z); af[3] = f2bf(xa.w);
            af[4] = f2bf(xb.x); af[5] = f2bf(xb.y);
            af[6] = f2bf(xb.z); af[7] = f2bf(xb.w);
            const int cb = kh * 4 + quad;
#pragma unroll
            for (int nt = 0; nt < 6; nt++) {
                const int n = colhalf * 96 + nt * 16 + l16;
                bf16x8 bf = *(const bf16x8*)(Bb + n * 128 + ((cb ^ (n & 7))) * 16);
                acc[nt] = __builtin_amdgcn_mfma_f32_16x16x32_bf16(af, bf, acc[nt], 0, 0, 0);
            }
        }
    }

#pragma unroll
    for (int nt = 0; nt < 6; nt++) {
        const int c = colhalf * 96 + nt * 16 + l16;
#pragma unroll
        for (int r = 0; r < 4; r++) {
            const int m = m0blk + rowhalf * 16 + quad * 4 + r;
            bf16_t val = f2bf(acc[nt][r]);
            if (c < 64) {
                Qb[(size_t)m * H_ + c] = val;
            } else if (c < 128) {
                Kb[(size_t)m * H_ + (c - 64)] = val;
            } else {
                const int b = m >> 11, n = m & 2047, h = c - 128;
                Vt[((size_t)b * H_ + h) * N_ + n] = val;
            }
        }
    }
}

// ---------------------------------------------------------------------------
// Kernel 3: flash attention (R4 body; blockIdx.z masked for dup).
// ---------------------------------------------------------------------------
__launch_bounds__(256, 4)
__global__ void attn_kernel(const bf16_t* __restrict__ Qb,
                            const bf16_t* __restrict__ Kb,
                            const bf16_t* __restrict__ Vt,
                            float* __restrict__ Out) {
    const int x = blockIdx.x;
    const int b = blockIdx.y;
    const int z = blockIdx.z & 1;        // dup copies alias z
    const int qt = z ? (127 - x) : x;
    const int q0 = qt * 16;

    const int wave = threadIdx.x >> 6;
    const int lane = threadIdx.x & 63;
    const int quad = lane >> 4;
    const int l16  = lane & 15;

    const bf16_t* Qp = Qb + ((size_t)b * N_ + q0) * H_;
    const bf16_t* Kp = Kb + (size_t)b * N_ * H_;
    const bf16_t* Vp = Vt + (size_t)b * H_ * N_;

    bf16x8 qf0 = *(const bf16x8*)(Qp + (size_t)l16 * H_ + quad * 8);
    bf16x8 qf1 = *(const bf16x8*)(Qp + (size_t)l16 * H_ + 32 + quad * 8);

    bf16x8 ones;
    {
        bf16_t one = f2bf(1.0f);
#pragma unroll
        for (int i = 0; i < 8; i++) ones[i] = one;
    }

    floatx4 o[4];
#pragma unroll
    for (int i = 0; i < 4; i++) o[i] = (floatx4){0.f, 0.f, 0.f, 0.f};
    floatx4 lsum = (floatx4){0.f, 0.f, 0.f, 0.f};

    __shared__ __align__(16) bf16_t Pl[4][16][32];
    __shared__ float Ol[3][16][64];
    __shared__ float Ll[3][16];

    const int kt_max = q0 >> 5;

    for (int kt = wave; kt <= kt_max; kt += 4) {
        const int k0 = kt << 5;

        const bf16_t* kp0 = Kp + (size_t)(k0 + l16) * H_ + quad * 8;
        const bf16_t* kp1 = kp0 + 16 * H_;
        bf16x8 kfa = *(const bf16x8*)kp0;
        bf16x8 kfb = *(const bf16x8*)(kp0 + 32);
        bf16x8 kfc = *(const bf16x8*)kp1;
        bf16x8 kfd = *(const bf16x8*)(kp1 + 32);
        const bf16_t* vp = Vp + (size_t)l16 * N_ + k0 + quad * 8;
        bf16x8 vf0 = *(const bf16x8*)(vp);
        bf16x8 vf1 = *(const bf16x8*)(vp + (size_t)16 * N_);
        bf16x8 vf2 = *(const bf16x8*)(vp + (size_t)32 * N_);
        bf16x8 vf3 = *(const bf16x8*)(vp + (size_t)48 * N_);

        floatx4 s0 = (floatx4){0.f, 0.f, 0.f, 0.f};
        floatx4 s1 = (floatx4){0.f, 0.f, 0.f, 0.f};
        s0 = __builtin_amdgcn_mfma_f32_16x16x32_bf16(qf0, kfa, s0, 0, 0, 0);
        s0 = __builtin_amdgcn_mfma_f32_16x16x32_bf16(qf1, kfb, s0, 0, 0, 0);
        s1 = __builtin_amdgcn_mfma_f32_16x16x32_bf16(qf0, kfc, s1, 0, 0, 0);
        s1 = __builtin_amdgcn_mfma_f32_16x16x32_bf16(qf1, kfd, s1, 0, 0, 0);

        float p[8];
        if (k0 + 31 <= q0) {
#pragma unroll
            for (int r = 0; r < 4; r++) {
                p[r]     = exp2f(s0[r]);
                p[4 + r] = exp2f(s1[r]);
            }
        } else {
            const int qrow = q0 + quad * 4;
#pragma unroll
            for (int r = 0; r < 4; r++) {
                p[r]     = (k0 + l16      <= qrow + r) ? exp2f(s0[r]) : 0.f;
                p[4 + r] = (k0 + 16 + l16 <= qrow + r) ? exp2f(s1[r]) : 0.f;
            }
        }

#pragma unroll
        for (int r = 0; r < 4; r++) {
            Pl[wave][quad * 4 + r][l16]      = f2bf(p[r]);
            Pl[wave][quad * 4 + r][16 + l16] = f2bf(p[4 + r]);
        }
        bf16x8 pf = *(const bf16x8*)(&Pl[wave][l16][quad * 8]);

        lsum = __builtin_amdgcn_mfma_f32_16x16x32_bf16(pf, ones, lsum, 0, 0, 0);
        o[0] = __builtin_amdgcn_mfma_f32_16x16x32_bf16(pf, vf0, o[0], 0, 0, 0);
        o[1] = __builtin_amdgcn_mfma_f32_16x16x32_bf16(pf, vf1, o[1], 0, 0, 0);
        o[2] = __builtin_amdgcn_mfma_f32_16x16x32_bf16(pf, vf2, o[2], 0, 0, 0);
        o[3] = __builtin_amdgcn_mfma_f32_16x16x32_bf16(pf, vf3, o[3], 0, 0, 0);
    }

    __syncthreads();
    if (wave != 0) {
#pragma unroll
        for (int nt = 0; nt < 4; nt++)
#pragma unroll
            for (int r = 0; r < 4; r++)
                Ol[wave - 1][quad * 4 + r][nt * 16 + l16] = o[nt][r];
        if (l16 == 0) {
#pragma unroll
            for (int r = 0; r < 4; r++)
                Ll[wave - 1][quad * 4 + r] = lsum[r];
        }
    }
    __syncthreads();
    if (wave == 0) {
#pragma unroll
        for (int r = 0; r < 4; r++) {
            const int row = quad * 4 + r;
            float l = lsum[r] + Ll[0][row] + Ll[1][row] + Ll[2][row];
            float inv = 1.0f / l;
#pragma unroll
            for (int nt = 0; nt < 4; nt++) {
                const int col = nt * 16 + l16;
                float v = o[nt][r] + Ol[0][row][col] + Ol[1][row][col] + Ol[2][row][col];
                Out[((size_t)b * N_ + q0 + row) * H_ + col] = v * inv;
            }
        }
    }
}

// ---------------------------------------------------------------------------
extern "C" void kernel_launch(void* const* d_in, const int* in_sizes, int n_in,
                              void* d_out, int out_size, void* d_ws, size_t ws_size,
                              hipStream_t stream) {
    const float* X  = (const float*)d_in[0];
    const float* Wq = (const float*)d_in[1];
    const float* Wk = (const float*)d_in[2];
    const float* Wv = (const float*)d_in[3];
    float* Out = (float*)d_out;

    char* ws = (char*)d_ws;
    bf16_t* Qb = (bf16_t*)(ws);
    bf16_t* Kb = (bf16_t*)(ws + (size_t)(2u << 20));
    bf16_t* Vt = (bf16_t*)(ws + (size_t)(4u << 20));
    bf16_t* Wt = (bf16_t*)(ws + (size_t)(6u << 20));

    hipLaunchKernelGGL(wt_kernel, dim3(768, 3), dim3(64), 0, stream, Wq, Wk, Wv, Wt);
    hipLaunchKernelGGL(proj_kernel, dim3(512 * PROJ_DUP), dim3(256), 0, stream,
                       X, Wt, Qb, Kb, Vt);
    hipLaunchKernelGGL(attn_kernel, dim3(64, 8, 2 * ATTN_DUP), dim3(256), 0, stream,
                       Qb, Kb, Vt, Out);
}

// Round 6
// 134.188 us; speedup vs baseline: 3.5218x; 3.5218x over previous
//
#include <hip/hip_runtime.h>
#include <stdint.h>

typedef __bf16 bf16_t;
typedef __bf16 bf16x8 __attribute__((ext_vector_type(8)));
typedef float floatx4 __attribute__((ext_vector_type(4)));

#define B_ 8
#define N_ 2048
#define D_ 768
#define H_ 64

__device__ __forceinline__ bf16_t f2bf(float f) {
    union { float f; uint32_t u; } v; v.f = f;
    uint32_t u = v.u;
    uint32_t r = (u + 0x7fffu + ((u >> 16) & 1u)) >> 16;
    union { unsigned short s; bf16_t b; } o; o.s = (unsigned short)r;
    return o.b;
}

__device__ __forceinline__ void async_cp16(void* l, const void* g) {
    __builtin_amdgcn_global_load_lds(
        (const __attribute__((address_space(1))) uint32_t*)g,
        (__attribute__((address_space(3))) uint32_t*)l, 16, 0, 0);
}

// ---------------------------------------------------------------------------
// Kernel 1: W transpose + cast (unchanged).
// ---------------------------------------------------------------------------
__global__ void wt_kernel(const float* __restrict__ Wq,
                          const float* __restrict__ Wk,
                          const float* __restrict__ Wv,
                          bf16_t* __restrict__ Wt) {
    const int h = threadIdx.x;
    const int k = blockIdx.x;
    const int s = blockIdx.y;
    const float* W = (s == 0) ? Wq : (s == 1) ? Wk : Wv;
    float v = W[k * H_ + h];
    if (s == 0) v *= 0.125f * 1.4426950408889634f;
    Wt[(size_t)(s * 64 + h) * D_ + k] = f2bf(v);
}

// ---------------------------------------------------------------------------
// Kernel 2: fused QKV projection (unchanged R4 body, real 512-block grid).
// ---------------------------------------------------------------------------
__launch_bounds__(256, 2)
__global__ void proj_kernel(const float* __restrict__ X,
                            const bf16_t* __restrict__ Wt,
                            bf16_t* __restrict__ Qb,
                            bf16_t* __restrict__ Kb,
                            bf16_t* __restrict__ Vt) {
    const int wave = threadIdx.x >> 6;
    const int lane = threadIdx.x & 63;
    const int quad = lane >> 4;
    const int l16  = lane & 15;
    const int rowhalf = wave & 1;
    const int colhalf = wave >> 1;
    const int m0blk = blockIdx.x * 32;

    __shared__ __align__(16) float  As[2][32 * 64];
    __shared__ __align__(16) bf16_t Bs[2][192 * 64];

    floatx4 acc[6];
#pragma unroll
    for (int i = 0; i < 6; i++) acc[i] = (floatx4){0.f, 0.f, 0.f, 0.f};

    auto stage = [&](int buf, int k0) {
#pragma unroll
        for (int i = 0; i < 2; i++) {
            const int r = (wave * 2 + i) * 4 + (lane >> 4);
            const int c = (lane & 15) ^ (r & 15);
            const float* g = X + (size_t)(m0blk + r) * D_ + k0 + c * 4;
            async_cp16((char*)&As[buf][0] + (wave * 2 + i) * 1024, g);
        }
#pragma unroll
        for (int i = 0; i < 6; i++) {
            const int r = (wave * 6 + i) * 8 + (lane >> 3);
            const int c = (lane & 7) ^ (r & 7);
            const bf16_t* g = Wt + (size_t)r * D_ + k0 + c * 8;
            async_cp16((char*)&Bs[buf][0] + (wave * 6 + i) * 1024, g);
        }
    };

    const int arow = rowhalf * 16 + l16;

    stage(0, 0);
    for (int ch = 0; ch < 12; ch++) {
        __syncthreads();
        if (ch + 1 < 12) stage((ch + 1) & 1, (ch + 1) * 64);

        const char* Ab = (const char*)&As[ch & 1][0];
        const char* Bb = (const char*)&Bs[ch & 1][0];
#pragma unroll
        for (int kh = 0; kh < 2; kh++) {
            const int c0 = kh * 8 + quad * 2;
            float4 xa = *(const float4*)(Ab + arow * 256 + ((c0 ^ l16) & 15) * 16);
            float4 xb = *(const float4*)(Ab + arow * 256 + (((c0 + 1) ^ l16) & 15) * 16);
            bf16x8 af;
            af[0] = f2bf(xa.x); af[1] = f2bf(xa.y);
            af[2] = f2bf(xa.z); af[3] = f2bf(xa.w);
            af[4] = f2bf(xb.x); af[5] = f2bf(xb.y);
            af[6] = f2bf(xb.z); af[7] = f2bf(xb.w);
            const int cb = kh * 4 + quad;
#pragma unroll
            for (int nt = 0; nt < 6; nt++) {
                const int n = colhalf * 96 + nt * 16 + l16;
                bf16x8 bf = *(const bf16x8*)(Bb + n * 128 + ((cb ^ (n & 7))) * 16);
                acc[nt] = __builtin_amdgcn_mfma_f32_16x16x32_bf16(af, bf, acc[nt], 0, 0, 0);
            }
        }
    }

#pragma unroll
    for (int nt = 0; nt < 6; nt++) {
        const int c = colhalf * 96 + nt * 16 + l16;
#pragma unroll
        for (int r = 0; r < 4; r++) {
            const int m = m0blk + rowhalf * 16 + quad * 4 + r;
            bf16_t val = f2bf(acc[nt][r]);
            if (c < 64) {
                Qb[(size_t)m * H_ + c] = val;
            } else if (c < 128) {
                Kb[(size_t)m * H_ + (c - 64)] = val;
            } else {
                const int b = m >> 11, n = m & 2047, h = c - 128;
                Vt[((size_t)b * H_ + h) * N_ + n] = val;
            }
        }
    }
}

// ---------------------------------------------------------------------------
// Kernel 3: flash attention, causal, plain-sum softmax (scale folded in Wq).
// R6: (a) sched_barrier(0) after the 8 K/V loads — R5 counters showed
// VGPR_Count=44, proving the scheduler sank V loads below the S-MFMAs and
// serialized the two memory latencies; the barrier pins all 8 loads in
// flight together (~110 VGPR, still under the 128 cap of (256,4)).
// (b) P tile padded to 56 bf16/row (112B = 7*16B): b128 reads 2-way (free),
// writes 8-way -> 4-way, alignment preserved.
// ---------------------------------------------------------------------------
__launch_bounds__(256, 4)
__global__ void attn_kernel(const bf16_t* __restrict__ Qb,
                            const bf16_t* __restrict__ Kb,
                            const bf16_t* __restrict__ Vt,
                            float* __restrict__ Out) {
    const int x = blockIdx.x;
    const int b = blockIdx.y;
    const int z = blockIdx.z;
    const int qt = z ? (127 - x) : x;
    const int q0 = qt * 16;

    const int wave = threadIdx.x >> 6;   // k-tile parity 0..3
    const int lane = threadIdx.x & 63;
    const int quad = lane >> 4;
    const int l16  = lane & 15;

    const bf16_t* Qp = Qb + ((size_t)b * N_ + q0) * H_;
    const bf16_t* Kp = Kb + (size_t)b * N_ * H_;
    const bf16_t* Vp = Vt + (size_t)b * H_ * N_;

    bf16x8 qf0 = *(const bf16x8*)(Qp + (size_t)l16 * H_ + quad * 8);
    bf16x8 qf1 = *(const bf16x8*)(Qp + (size_t)l16 * H_ + 32 + quad * 8);

    bf16x8 ones;
    {
        bf16_t one = f2bf(1.0f);
#pragma unroll
        for (int i = 0; i < 8; i++) ones[i] = one;
    }

    floatx4 o[4];
#pragma unroll
    for (int i = 0; i < 4; i++) o[i] = (floatx4){0.f, 0.f, 0.f, 0.f};
    floatx4 lsum = (floatx4){0.f, 0.f, 0.f, 0.f};

    __shared__ __align__(16) bf16_t Pl[4][16][56];   // 112B row stride
    __shared__ float Ol[3][16][64];
    __shared__ float Ll[3][16];

    const int kt_max = q0 >> 5;

    for (int kt = wave; kt <= kt_max; kt += 4) {
        const int k0 = kt << 5;

        // ---- issue ALL 8 K/V fragment loads; barrier pins them in flight ----
        const bf16_t* kp0 = Kp + (size_t)(k0 + l16) * H_ + quad * 8;
        const bf16_t* kp1 = kp0 + 16 * H_;
        bf16x8 kfa = *(const bf16x8*)kp0;
        bf16x8 kfb = *(const bf16x8*)(kp0 + 32);
        bf16x8 kfc = *(const bf16x8*)kp1;
        bf16x8 kfd = *(const bf16x8*)(kp1 + 32);
        const bf16_t* vp = Vp + (size_t)l16 * N_ + k0 + quad * 8;
        bf16x8 vf0 = *(const bf16x8*)(vp);
        bf16x8 vf1 = *(const bf16x8*)(vp + (size_t)16 * N_);
        bf16x8 vf2 = *(const bf16x8*)(vp + (size_t)32 * N_);
        bf16x8 vf3 = *(const bf16x8*)(vp + (size_t)48 * N_);
        __builtin_amdgcn_sched_barrier(0);   // no load sinks below this point

        // ---- S = Q K^T ----
        floatx4 s0 = (floatx4){0.f, 0.f, 0.f, 0.f};
        floatx4 s1 = (floatx4){0.f, 0.f, 0.f, 0.f};
        s0 = __builtin_amdgcn_mfma_f32_16x16x32_bf16(qf0, kfa, s0, 0, 0, 0);
        s0 = __builtin_amdgcn_mfma_f32_16x16x32_bf16(qf1, kfb, s0, 0, 0, 0);
        s1 = __builtin_amdgcn_mfma_f32_16x16x32_bf16(qf0, kfc, s1, 0, 0, 0);
        s1 = __builtin_amdgcn_mfma_f32_16x16x32_bf16(qf1, kfd, s1, 0, 0, 0);

        // ---- P = exp2(S), causal mask on diagonal tile only ----
        float p[8];
        if (k0 + 31 <= q0) {
#pragma unroll
            for (int r = 0; r < 4; r++) {
                p[r]     = exp2f(s0[r]);
                p[4 + r] = exp2f(s1[r]);
            }
        } else {
            const int qrow = q0 + quad * 4;
#pragma unroll
            for (int r = 0; r < 4; r++) {
                p[r]     = (k0 + l16      <= qrow + r) ? exp2f(s0[r]) : 0.f;
                p[4 + r] = (k0 + 16 + l16 <= qrow + r) ? exp2f(s1[r]) : 0.f;
            }
        }

        // ---- P: C-layout -> A-layout via wave-private LDS ----
#pragma unroll
        for (int r = 0; r < 4; r++) {
            Pl[wave][quad * 4 + r][l16]      = f2bf(p[r]);
            Pl[wave][quad * 4 + r][16 + l16] = f2bf(p[4 + r]);
        }
        bf16x8 pf = *(const bf16x8*)(&Pl[wave][l16][quad * 8]);

        // ---- l += P*1, O += P V ----
        lsum = __builtin_amdgcn_mfma_f32_16x16x32_bf16(pf, ones, lsum, 0, 0, 0);
        o[0] = __builtin_amdgcn_mfma_f32_16x16x32_bf16(pf, vf0, o[0], 0, 0, 0);
        o[1] = __builtin_amdgcn_mfma_f32_16x16x32_bf16(pf, vf1, o[1], 0, 0, 0);
        o[2] = __builtin_amdgcn_mfma_f32_16x16x32_bf16(pf, vf2, o[2], 0, 0, 0);
        o[3] = __builtin_amdgcn_mfma_f32_16x16x32_bf16(pf, vf3, o[3], 0, 0, 0);
    }

    __syncthreads();
    if (wave != 0) {
#pragma unroll
        for (int nt = 0; nt < 4; nt++)
#pragma unroll
            for (int r = 0; r < 4; r++)
                Ol[wave - 1][quad * 4 + r][nt * 16 + l16] = o[nt][r];
        if (l16 == 0) {
#pragma unroll
            for (int r = 0; r < 4; r++)
                Ll[wave - 1][quad * 4 + r] = lsum[r];
        }
    }
    __syncthreads();
    if (wave == 0) {
#pragma unroll
        for (int r = 0; r < 4; r++) {
            const int row = quad * 4 + r;
            float l = lsum[r] + Ll[0][row] + Ll[1][row] + Ll[2][row];
            float inv = 1.0f / l;
#pragma unroll
            for (int nt = 0; nt < 4; nt++) {
                const int col = nt * 16 + l16;
                float v = o[nt][r] + Ol[0][row][col] + Ol[1][row][col] + Ol[2][row][col];
                Out[((size_t)b * N_ + q0 + row) * H_ + col] = v * inv;
            }
        }
    }
}

// ---------------------------------------------------------------------------
extern "C" void kernel_launch(void* const* d_in, const int* in_sizes, int n_in,
                              void* d_out, int out_size, void* d_ws, size_t ws_size,
                              hipStream_t stream) {
    const float* X  = (const float*)d_in[0];
    const float* Wq = (const float*)d_in[1];
    const float* Wk = (const float*)d_in[2];
    const float* Wv = (const float*)d_in[3];
    float* Out = (float*)d_out;

    char* ws = (char*)d_ws;
    bf16_t* Qb = (bf16_t*)(ws);
    bf16_t* Kb = (bf16_t*)(ws + (size_t)(2u << 20));
    bf16_t* Vt = (bf16_t*)(ws + (size_t)(4u << 20));
    bf16_t* Wt = (bf16_t*)(ws + (size_t)(6u << 20));

    hipLaunchKernelGGL(wt_kernel, dim3(768, 3), dim3(64), 0, stream, Wq, Wk, Wv, Wt);
    hipLaunchKernelGGL(proj_kernel, dim3(512), dim3(256), 0, stream, X, Wt, Qb, Kb, Vt);
    hipLaunchKernelGGL(attn_kernel, dim3(64, 8, 2), dim3(256), 0, stream, Qb, Kb, Vt, Out);
}

// Round 7
// 126.136 us; speedup vs baseline: 3.7466x; 1.0638x over previous
//
#include <hip/hip_runtime.h>
#include <stdint.h>

typedef __bf16 bf16_t;
typedef __bf16 bf16x8 __attribute__((ext_vector_type(8)));
typedef float floatx4 __attribute__((ext_vector_type(4)));

#define B_ 8
#define N_ 2048
#define D_ 768
#define H_ 64

// raw s_waitcnt imms (gfx9 encoding): vm[3:0]=bits3:0, exp=bits6:4, lgkm=bits11:8
#define WAIT_VM8()   { __builtin_amdgcn_sched_barrier(0); __builtin_amdgcn_s_waitcnt(0x0F78); __builtin_amdgcn_sched_barrier(0); }
#define WAIT_VM0()   { __builtin_amdgcn_sched_barrier(0); __builtin_amdgcn_s_waitcnt(0x0F70); __builtin_amdgcn_sched_barrier(0); }
#define WAIT_LGKM0() { __builtin_amdgcn_sched_barrier(0); __builtin_amdgcn_s_waitcnt(0xC07F); __builtin_amdgcn_sched_barrier(0); }

__device__ __forceinline__ bf16_t f2bf(float f) {
    union { float f; uint32_t u; } v; v.f = f;
    uint32_t u = v.u;
    uint32_t r = (u + 0x7fffu + ((u >> 16) & 1u)) >> 16;
    union { unsigned short s; bf16_t b; } o; o.s = (unsigned short)r;
    return o.b;
}

__device__ __forceinline__ void async_cp16(void* l, const void* g) {
    __builtin_amdgcn_global_load_lds(
        (const __attribute__((address_space(1))) uint32_t*)g,
        (__attribute__((address_space(3))) uint32_t*)l, 16, 0, 0);
}

// ---------------------------------------------------------------------------
// Kernel 1: W transpose + cast (unchanged).
// ---------------------------------------------------------------------------
__global__ void wt_kernel(const float* __restrict__ Wq,
                          const float* __restrict__ Wk,
                          const float* __restrict__ Wv,
                          bf16_t* __restrict__ Wt) {
    const int h = threadIdx.x;
    const int k = blockIdx.x;
    const int s = blockIdx.y;
    const float* W = (s == 0) ? Wq : (s == 1) ? Wk : Wv;
    float v = W[k * H_ + h];
    if (s == 0) v *= 0.125f * 1.4426950408889634f;
    Wt[(size_t)(s * 64 + h) * D_ + k] = f2bf(v);
}

// ---------------------------------------------------------------------------
// Kernel 2: fused QKV projection (unchanged — R5 showed it's <6us/run).
// ---------------------------------------------------------------------------
__launch_bounds__(256, 2)
__global__ void proj_kernel(const float* __restrict__ X,
                            const bf16_t* __restrict__ Wt,
                            bf16_t* __restrict__ Qb,
                            bf16_t* __restrict__ Kb,
                            bf16_t* __restrict__ Vt) {
    const int wave = threadIdx.x >> 6;
    const int lane = threadIdx.x & 63;
    const int quad = lane >> 4;
    const int l16  = lane & 15;
    const int rowhalf = wave & 1;
    const int colhalf = wave >> 1;
    const int m0blk = blockIdx.x * 32;

    __shared__ __align__(16) float  As[2][32 * 64];
    __shared__ __align__(16) bf16_t Bs[2][192 * 64];

    floatx4 acc[6];
#pragma unroll
    for (int i = 0; i < 6; i++) acc[i] = (floatx4){0.f, 0.f, 0.f, 0.f};

    auto stage = [&](int buf, int k0) {
#pragma unroll
        for (int i = 0; i < 2; i++) {
            const int r = (wave * 2 + i) * 4 + (lane >> 4);
            const int c = (lane & 15) ^ (r & 15);
            const float* g = X + (size_t)(m0blk + r) * D_ + k0 + c * 4;
            async_cp16((char*)&As[buf][0] + (wave * 2 + i) * 1024, g);
        }
#pragma unroll
        for (int i = 0; i < 6; i++) {
            const int r = (wave * 6 + i) * 8 + (lane >> 3);
            const int c = (lane & 7) ^ (r & 7);
            const bf16_t* g = Wt + (size_t)r * D_ + k0 + c * 8;
            async_cp16((char*)&Bs[buf][0] + (wave * 6 + i) * 1024, g);
        }
    };

    const int arow = rowhalf * 16 + l16;

    stage(0, 0);
    for (int ch = 0; ch < 12; ch++) {
        __syncthreads();
        if (ch + 1 < 12) stage((ch + 1) & 1, (ch + 1) * 64);

        const char* Ab = (const char*)&As[ch & 1][0];
        const char* Bb = (const char*)&Bs[ch & 1][0];
#pragma unroll
        for (int kh = 0; kh < 2; kh++) {
            const int c0 = kh * 8 + quad * 2;
            float4 xa = *(const float4*)(Ab + arow * 256 + ((c0 ^ l16) & 15) * 16);
            float4 xb = *(const float4*)(Ab + arow * 256 + (((c0 + 1) ^ l16) & 15) * 16);
            bf16x8 af;
            af[0] = f2bf(xa.x); af[1] = f2bf(xa.y);
            af[2] = f2bf(xa.z); af[3] = f2bf(xa.w);
            af[4] = f2bf(xb.x); af[5] = f2bf(xb.y);
            af[6] = f2bf(xb.z); af[7] = f2bf(xb.w);
            const int cb = kh * 4 + quad;
#pragma unroll
            for (int nt = 0; nt < 6; nt++) {
                const int n = colhalf * 96 + nt * 16 + l16;
                bf16x8 bf = *(const bf16x8*)(Bb + n * 128 + ((cb ^ (n & 7))) * 16);
                acc[nt] = __builtin_amdgcn_mfma_f32_16x16x32_bf16(af, bf, acc[nt], 0, 0, 0);
            }
        }
    }

#pragma unroll
    for (int nt = 0; nt < 6; nt++) {
        const int c = colhalf * 96 + nt * 16 + l16;
#pragma unroll
        for (int r = 0; r < 4; r++) {
            const int m = m0blk + rowhalf * 16 + quad * 4 + r;
            bf16_t val = f2bf(acc[nt][r]);
            if (c < 64) {
                Qb[(size_t)m * H_ + c] = val;
            } else if (c < 128) {
                Kb[(size_t)m * H_ + (c - 64)] = val;
            } else {
                const int b = m >> 11, n = m & 2047, h = c - 128;
                Vt[((size_t)b * H_ + h) * N_ + n] = val;
            }
        }
    }
}

// ---------------------------------------------------------------------------
// Kernel 3: flash attention, causal, plain-sum softmax.
// R7: wave-private depth-2 async K/V staging via global_load_lds.
// Each wave owns k-tiles {wave, wave+4, ...} (4-way k-split as before) and
// prefetches its own tiles into a private 2x8KB LDS slice — NO barriers in
// the loop, so no m97-style drain.  Manual s_waitcnt vmcnt(8) waits only
// for the current tile's 8 DMA issues (next 2 tiles stay in flight) —
// the AITER fine-grained-vmcnt pattern.  XOR-swizzled DMA source addresses
// give conflict-free ds_read_b128 fragment reads (2 lanes/bank = free).
// Merge arrays alias the staging region (used strictly after the loop).
// ---------------------------------------------------------------------------
__launch_bounds__(256, 2)
__global__ void attn_kernel(const bf16_t* __restrict__ Qb,
                            const bf16_t* __restrict__ Kb,
                            const bf16_t* __restrict__ Vt,
                            float* __restrict__ Out) {
    const int x = blockIdx.x;
    const int b = blockIdx.y;
    const int z = blockIdx.z;
    const int qt = z ? (127 - x) : x;    // causal load-balance pairing
    const int q0 = qt * 16;

    const int wave = threadIdx.x >> 6;   // k-tile parity 0..3
    const int lane = threadIdx.x & 63;
    const int quad = lane >> 4;
    const int l16  = lane & 15;

    // LDS: staging 4 waves x 2 bufs x (K 4KB + V 4KB) = 64KB; Pl after it.
    // Ol/Ll alias the staging region (merge runs after all staging reads).
    __shared__ __align__(16) char smem[4 * 16384 + 4 * 16 * 56 * 2];
    char* stg = smem;
    bf16_t* Pl = (bf16_t*)(smem + 65536);          // [4][16][56]
    float* Ol  = (float*)smem;                     // [3][16][64]
    float* Ll  = (float*)(smem + 12288);           // [3][16]

    const bf16_t* Qp = Qb + ((size_t)b * N_ + q0) * H_;
    const char* Kp = (const char*)(Kb + (size_t)b * N_ * H_);
    const char* Vp = (const char*)(Vt + (size_t)b * H_ * N_);

    bf16x8 qf0 = *(const bf16x8*)(Qp + (size_t)l16 * H_ + quad * 8);
    bf16x8 qf1 = *(const bf16x8*)(Qp + (size_t)l16 * H_ + 32 + quad * 8);

    bf16x8 ones;
    {
        bf16_t one = f2bf(1.0f);
#pragma unroll
        for (int i = 0; i < 8; i++) ones[i] = one;
    }

    floatx4 o[4];
#pragma unroll
    for (int i = 0; i < 4; i++) o[i] = (floatx4){0.f, 0.f, 0.f, 0.f};
    floatx4 lsum = (floatx4){0.f, 0.f, 0.f, 0.f};

    char* mybase = stg + wave * 16384;   // 2 bufs x 8192 (K@0, V@4096)

    // per-tile DMA: 8 issues of 1KB.  K image: row r (key) x 8 cells of 16B,
    // cell c holds logical h-chunk c^(r&7).  V image: row r (=h) x 4 cells,
    // cell c holds logical key-chunk c^(r&3).
    const int rK = lane >> 3, cK = lane & 7;
    const int rV = lane >> 2, cV = lane & 3;
    auto stage_kv = [&](int k0, char* buf) {
#pragma unroll
        for (int i = 0; i < 4; i++) {
            const int r = i * 8 + rK;
            const char* g = Kp + (size_t)(k0 + r) * 128 + (cK ^ (r & 7)) * 16;
            async_cp16(buf + i * 1024, g);
        }
#pragma unroll
        for (int i = 0; i < 4; i++) {
            const int r = i * 16 + rV;
            const char* g = Vp + (size_t)r * 4096 + (size_t)k0 * 2 + (cV ^ (r & 3)) * 16;
            async_cp16(buf + 4096 + i * 1024, g);
        }
    };

    const int ktm = q0 >> 5;             // inclusive max k-tile

    if (wave <= ktm)     stage_kv(wave << 5,       mybase);
    if (wave + 4 <= ktm) stage_kv((wave + 4) << 5, mybase + 8192);

    for (int kt = wave; kt <= ktm; kt += 4) {
        const int k0 = kt << 5;
        const int buf = (((kt - wave) >> 2) & 1);
        const char* kb = mybase + buf * 8192;
        const char* vb = kb + 4096;

        // wait for THIS tile's 8 DMAs; leave the next tile's 8 in flight
        if (kt + 4 <= ktm) { WAIT_VM8(); } else { WAIT_VM0(); }

        // ---- fragment reads from staged LDS (conflict-free) ----
        const int krow = l16 * 128;
        bf16x8 kfa = *(const bf16x8*)(kb + krow        + ((quad    ) ^ (l16 & 7)) * 16);
        bf16x8 kfb = *(const bf16x8*)(kb + krow        + ((quad + 4) ^ (l16 & 7)) * 16);
        bf16x8 kfc = *(const bf16x8*)(kb + krow + 2048 + ((quad    ) ^ (l16 & 7)) * 16);
        bf16x8 kfd = *(const bf16x8*)(kb + krow + 2048 + ((quad + 4) ^ (l16 & 7)) * 16);
        bf16x8 vf0 = *(const bf16x8*)(vb + (l16     ) * 64 + (quad ^ (l16 & 3)) * 16);
        bf16x8 vf1 = *(const bf16x8*)(vb + (l16 + 16) * 64 + (quad ^ (l16 & 3)) * 16);
        bf16x8 vf2 = *(const bf16x8*)(vb + (l16 + 32) * 64 + (quad ^ (l16 & 3)) * 16);
        bf16x8 vf3 = *(const bf16x8*)(vb + (l16 + 48) * 64 + (quad ^ (l16 & 3)) * 16);

        // drain LDS reads, then retarget this buffer with tile kt+8's DMA
        WAIT_LGKM0();
        if (kt + 8 <= ktm) stage_kv((kt + 8) << 5, mybase + buf * 8192);

        // ---- S = Q K^T ----
        floatx4 s0 = (floatx4){0.f, 0.f, 0.f, 0.f};
        floatx4 s1 = (floatx4){0.f, 0.f, 0.f, 0.f};
        s0 = __builtin_amdgcn_mfma_f32_16x16x32_bf16(qf0, kfa, s0, 0, 0, 0);
        s0 = __builtin_amdgcn_mfma_f32_16x16x32_bf16(qf1, kfb, s0, 0, 0, 0);
        s1 = __builtin_amdgcn_mfma_f32_16x16x32_bf16(qf0, kfc, s1, 0, 0, 0);
        s1 = __builtin_amdgcn_mfma_f32_16x16x32_bf16(qf1, kfd, s1, 0, 0, 0);

        // ---- P = exp2(S), causal mask on diagonal tile only ----
        float p[8];
        if (k0 + 31 <= q0) {
#pragma unroll
            for (int r = 0; r < 4; r++) {
                p[r]     = exp2f(s0[r]);
                p[4 + r] = exp2f(s1[r]);
            }
        } else {
            const int qrow = q0 + quad * 4;
#pragma unroll
            for (int r = 0; r < 4; r++) {
                p[r]     = (k0 + l16      <= qrow + r) ? exp2f(s0[r]) : 0.f;
                p[4 + r] = (k0 + 16 + l16 <= qrow + r) ? exp2f(s1[r]) : 0.f;
            }
        }

        // ---- P: C-layout -> A-layout via wave-private LDS ----
        bf16_t* Pw = Pl + wave * 16 * 56;
#pragma unroll
        for (int r = 0; r < 4; r++) {
            Pw[(quad * 4 + r) * 56 + l16]      = f2bf(p[r]);
            Pw[(quad * 4 + r) * 56 + 16 + l16] = f2bf(p[4 + r]);
        }
        bf16x8 pf = *(const bf16x8*)(Pw + l16 * 56 + quad * 8);

        // ---- l += P*1, O += P V ----
        lsum = __builtin_amdgcn_mfma_f32_16x16x32_bf16(pf, ones, lsum, 0, 0, 0);
        o[0] = __builtin_amdgcn_mfma_f32_16x16x32_bf16(pf, vf0, o[0], 0, 0, 0);
        o[1] = __builtin_amdgcn_mfma_f32_16x16x32_bf16(pf, vf1, o[1], 0, 0, 0);
        o[2] = __builtin_amdgcn_mfma_f32_16x16x32_bf16(pf, vf2, o[2], 0, 0, 0);
        o[3] = __builtin_amdgcn_mfma_f32_16x16x32_bf16(pf, vf3, o[3], 0, 0, 0);
    }

    // ---- merge 4-way k-split partials (Ol/Ll alias staging; loop done) ----
    __syncthreads();
    if (wave != 0) {
        float* Ow = Ol + (wave - 1) * 16 * 64;
#pragma unroll
        for (int nt = 0; nt < 4; nt++)
#pragma unroll
            for (int r = 0; r < 4; r++)
                Ow[(quad * 4 + r) * 64 + nt * 16 + l16] = o[nt][r];
        if (l16 == 0) {
#pragma unroll
            for (int r = 0; r < 4; r++)
                Ll[(wave - 1) * 16 + quad * 4 + r] = lsum[r];
        }
    }
    __syncthreads();
    if (wave == 0) {
#pragma unroll
        for (int r = 0; r < 4; r++) {
            const int row = quad * 4 + r;
            float l = lsum[r] + Ll[row] + Ll[16 + row] + Ll[32 + row];
            float inv = 1.0f / l;
#pragma unroll
            for (int nt = 0; nt < 4; nt++) {
                const int col = nt * 16 + l16;
                float v = o[nt][r] + Ol[row * 64 + col]
                        + Ol[(16 + row) * 64 + col] + Ol[(32 + row) * 64 + col];
                Out[((size_t)b * N_ + q0 + row) * H_ + col] = v * inv;
            }
        }
    }
}

// ---------------------------------------------------------------------------
extern "C" void kernel_launch(void* const* d_in, const int* in_sizes, int n_in,
                              void* d_out, int out_size, void* d_ws, size_t ws_size,
                              hipStream_t stream) {
    const float* X  = (const float*)d_in[0];
    const float* Wq = (const float*)d_in[1];
    const float* Wk = (const float*)d_in[2];
    const float* Wv = (const float*)d_in[3];
    float* Out = (float*)d_out;

    char* ws = (char*)d_ws;
    bf16_t* Qb = (bf16_t*)(ws);
    bf16_t* Kb = (bf16_t*)(ws + (size_t)(2u << 20));
    bf16_t* Vt = (bf16_t*)(ws + (size_t)(4u << 20));
    bf16_t* Wt = (bf16_t*)(ws + (size_t)(6u << 20));

    hipLaunchKernelGGL(wt_kernel, dim3(768, 3), dim3(64), 0, stream, Wq, Wk, Wv, Wt);
    hipLaunchKernelGGL(proj_kernel, dim3(512), dim3(256), 0, stream, X, Wt, Qb, Kb, Vt);
    hipLaunchKernelGGL(attn_kernel, dim3(64, 8, 2), dim3(256), 0, stream, Qb, Kb, Vt, Out);
}

// Round 8
// 120.950 us; speedup vs baseline: 3.9072x; 1.0429x over previous
//
#include <hip/hip_runtime.h>
#include <stdint.h>

typedef __bf16 bf16_t;
typedef __bf16 bf16x4 __attribute__((ext_vector_type(4)));
typedef __bf16 bf16x8 __attribute__((ext_vector_type(8)));
typedef float floatx4 __attribute__((ext_vector_type(4)));
typedef float floatx16 __attribute__((ext_vector_type(16)));

#define B_ 8
#define N_ 2048
#define D_ 768
#define H_ 64

// raw s_waitcnt imms (gfx9): vm[3:0]=bits3:0, vm[5:4]=bits15:14, lgkm=bits11:8
#define WAIT_VM8()   { __builtin_amdgcn_sched_barrier(0); __builtin_amdgcn_s_waitcnt(0x0F78); __builtin_amdgcn_sched_barrier(0); }
#define WAIT_VM0()   { __builtin_amdgcn_sched_barrier(0); __builtin_amdgcn_s_waitcnt(0x0F70); __builtin_amdgcn_sched_barrier(0); }
#define WAIT_LGKM0() { __builtin_amdgcn_sched_barrier(0); __builtin_amdgcn_s_waitcnt(0xC07F); __builtin_amdgcn_sched_barrier(0); }

__device__ __forceinline__ bf16_t f2bf(float f) {
    union { float f; uint32_t u; } v; v.f = f;
    uint32_t u = v.u;
    uint32_t r = (u + 0x7fffu + ((u >> 16) & 1u)) >> 16;
    union { unsigned short s; bf16_t b; } o; o.s = (unsigned short)r;
    return o.b;
}

__device__ __forceinline__ void async_cp16(void* l, const void* g) {
    __builtin_amdgcn_global_load_lds(
        (const __attribute__((address_space(1))) uint32_t*)g,
        (__attribute__((address_space(3))) uint32_t*)l, 16, 0, 0);
}

// ---------------------------------------------------------------------------
// Kernel 1: W transpose + cast (unchanged).
// ---------------------------------------------------------------------------
__global__ void wt_kernel(const float* __restrict__ Wq,
                          const float* __restrict__ Wk,
                          const float* __restrict__ Wv,
                          bf16_t* __restrict__ Wt) {
    const int h = threadIdx.x;
    const int k = blockIdx.x;
    const int s = blockIdx.y;
    const float* W = (s == 0) ? Wq : (s == 1) ? Wk : Wv;
    float v = W[k * H_ + h];
    if (s == 0) v *= 0.125f * 1.4426950408889634f;
    Wt[(size_t)(s * 64 + h) * D_ + k] = f2bf(v);
}

// ---------------------------------------------------------------------------
// Kernel 2: fused QKV projection (unchanged — measured <6us/run in R5).
// ---------------------------------------------------------------------------
__launch_bounds__(256, 2)
__global__ void proj_kernel(const float* __restrict__ X,
                            const bf16_t* __restrict__ Wt,
                            bf16_t* __restrict__ Qb,
                            bf16_t* __restrict__ Kb,
                            bf16_t* __restrict__ Vt) {
    const int wave = threadIdx.x >> 6;
    const int lane = threadIdx.x & 63;
    const int quad = lane >> 4;
    const int l16  = lane & 15;
    const int rowhalf = wave & 1;
    const int colhalf = wave >> 1;
    const int m0blk = blockIdx.x * 32;

    __shared__ __align__(16) float  As[2][32 * 64];
    __shared__ __align__(16) bf16_t Bs[2][192 * 64];

    floatx4 acc[6];
#pragma unroll
    for (int i = 0; i < 6; i++) acc[i] = (floatx4){0.f, 0.f, 0.f, 0.f};

    auto stage = [&](int buf, int k0) {
#pragma unroll
        for (int i = 0; i < 2; i++) {
            const int r = (wave * 2 + i) * 4 + (lane >> 4);
            const int c = (lane & 15) ^ (r & 15);
            const float* g = X + (size_t)(m0blk + r) * D_ + k0 + c * 4;
            async_cp16((char*)&As[buf][0] + (wave * 2 + i) * 1024, g);
        }
#pragma unroll
        for (int i = 0; i < 6; i++) {
            const int r = (wave * 6 + i) * 8 + (lane >> 3);
            const int c = (lane & 7) ^ (r & 7);
            const bf16_t* g = Wt + (size_t)r * D_ + k0 + c * 8;
            async_cp16((char*)&Bs[buf][0] + (wave * 6 + i) * 1024, g);
        }
    };

    const int arow = rowhalf * 16 + l16;

    stage(0, 0);
    for (int ch = 0; ch < 12; ch++) {
        __syncthreads();
        if (ch + 1 < 12) stage((ch + 1) & 1, (ch + 1) * 64);

        const char* Ab = (const char*)&As[ch & 1][0];
        const char* Bb = (const char*)&Bs[ch & 1][0];
#pragma unroll
        for (int kh = 0; kh < 2; kh++) {
            const int c0 = kh * 8 + quad * 2;
            float4 xa = *(const float4*)(Ab + arow * 256 + ((c0 ^ l16) & 15) * 16);
            float4 xb = *(const float4*)(Ab + arow * 256 + (((c0 + 1) ^ l16) & 15) * 16);
            bf16x8 af;
            af[0] = f2bf(xa.x); af[1] = f2bf(xa.y);
            af[2] = f2bf(xa.z); af[3] = f2bf(xa.w);
            af[4] = f2bf(xb.x); af[5] = f2bf(xb.y);
            af[6] = f2bf(xb.z); af[7] = f2bf(xb.w);
            const int cb = kh * 4 + quad;
#pragma unroll
            for (int nt = 0; nt < 6; nt++) {
                const int n = colhalf * 96 + nt * 16 + l16;
                bf16x8 bf = *(const bf16x8*)(Bb + n * 128 + ((cb ^ (n & 7))) * 16);
                acc[nt] = __builtin_amdgcn_mfma_f32_16x16x32_bf16(af, bf, acc[nt], 0, 0, 0);
            }
        }
    }

#pragma unroll
    for (int nt = 0; nt < 6; nt++) {
        const int c = colhalf * 96 + nt * 16 + l16;
#pragma unroll
        for (int r = 0; r < 4; r++) {
            const int m = m0blk + rowhalf * 16 + quad * 4 + r;
            bf16_t val = f2bf(acc[nt][r]);
            if (c < 64) {
                Qb[(size_t)m * H_ + c] = val;
            } else if (c < 128) {
                Kb[(size_t)m * H_ + (c - 64)] = val;
            } else {
                const int b = m >> 11, n = m & 2047, h = c - 128;
                Vt[((size_t)b * H_ + h) * N_ + n] = val;
            }
        }
    }
}

// ---------------------------------------------------------------------------
// Kernel 3 (R8): flash attention on 32x32x16 MFMA.
// q-tile 32 rows/block; 4 waves = 4-way k-split, wave-private depth-2 async
// staging (R7 pattern, no in-loop barriers).  S computed TRANSPOSED
// (A=K, B=Q) so P packs to LDS as 4x ds_write_b64 of consecutive keys;
// PV reads P back as A-frags via 4x ds_read_b64.  lsum via register adds
// + shfl_xor(32).  Plain-sum softmax (scale folded into Wq) — exact.
// LDS 72KB -> 2 blocks/CU; grid 512 = all resident, z-paired causal balance.
// ---------------------------------------------------------------------------
__launch_bounds__(256, 2)
__global__ void attn_kernel(const bf16_t* __restrict__ Qb,
                            const bf16_t* __restrict__ Kb,
                            const bf16_t* __restrict__ Vt,
                            float* __restrict__ Out) {
    const int x = blockIdx.x;            // 0..31
    const int b = blockIdx.y;            // 0..7
    const int z = blockIdx.z;            // 0..1
    const int qt = z ? (63 - x) : x;     // 64 q-tiles of 32 rows
    const int q0 = qt * 32;

    const int wave = threadIdx.x >> 6;   // k-split parity 0..3
    const int lane = threadIdx.x & 63;
    const int hi   = lane >> 5;          // 0/1
    const int lq   = lane & 31;

    // LDS: staging 4 waves x 2 bufs x (K 4KB | V 4KB) = 64KB, then P 4x2KB.
    // Merge arrays alias staging (used strictly after the loop + barrier).
    __shared__ __align__(16) char smem[4 * 16384 + 4 * 2048];
    char* mybase = smem + wave * 16384;
    char* Pimg   = smem + 65536 + wave * 2048;    // 32 rows x 64B
    float* Ol = (float*)smem;                     // 3 x 32x64 fp32
    float* Ll = (float*)(smem + 24576);           // 4 x 32 fp32

    // Q B-frags (rows q=lq, h-chunks of 8 per hi), 4 k-steps of 16h
    const bf16_t* qrow = Qb + ((size_t)b * N_ + q0 + lq) * H_ + hi * 8;
    bf16x8 qf0 = *(const bf16x8*)(qrow);
    bf16x8 qf1 = *(const bf16x8*)(qrow + 16);
    bf16x8 qf2 = *(const bf16x8*)(qrow + 32);
    bf16x8 qf3 = *(const bf16x8*)(qrow + 48);

    floatx16 o0, o1;
#pragma unroll
    for (int i = 0; i < 16; i++) { o0[i] = 0.f; o1[i] = 0.f; }
    float ls = 0.f;

    const bf16_t* KpB = Kb + (size_t)b * N_ * H_;
    const bf16_t* VpB = Vt + (size_t)b * H_ * N_;

    // DMA: K image 32 rows x 128B (8 cells), logical cell c at phys c^mK(r);
    //      V image 64 rows x 64B (4 cells), logical cell c at phys c^mV(h).
    const int rK = lane >> 3, cK = lane & 7;
    const int rV = lane >> 2, cV = lane & 3;
    const int mVl = (rV & 3) ^ ((rV & 4) >> 2);   // h bits 0-2 only
    auto stage_kv = [&](int k0, char* buf) {
#pragma unroll
        for (int i = 0; i < 4; i++) {
            const int r = i * 8 + rK;
            const int mk = rK ^ (((i & 1) << 2));         // (r&7)^((r&8)>>1)
            async_cp16(buf + i * 1024,
                       KpB + (size_t)(k0 + r) * H_ + (cK ^ mk) * 8);
        }
#pragma unroll
        for (int i = 0; i < 4; i++) {
            const int h = i * 16 + rV;
            async_cp16(buf + 4096 + i * 1024,
                       VpB + (size_t)h * N_ + k0 + (cV ^ mVl) * 8);
        }
    };

    const int ktm = qt;                  // inclusive max k-tile
    if (wave <= ktm)     stage_kv(wave * 32, mybase);
    if (wave + 4 <= ktm) stage_kv((wave + 4) * 32, mybase + 8192);

    const int mK = (lq & 7) ^ ((lq & 8) >> 1);
    const int m8 = (lq & 7) ^ ((lq & 8) >> 1);    // P sub-cell swizzle

    for (int kt = wave; kt <= ktm; kt += 4) {
        const int k0 = kt * 32;
        char* kb = mybase + (((((kt - wave) >> 2) & 1)) ? 8192 : 0);
        char* vb = kb + 4096;

        if (kt + 4 <= ktm) { WAIT_VM8(); } else { WAIT_VM0(); }

        // K A-frags: row=key=lq, k-step s covers h = s*16 + hi*8 + j
        bf16x8 kf0 = *(const bf16x8*)(kb + lq * 128 + (((0 + hi) ^ mK) * 16));
        bf16x8 kf1 = *(const bf16x8*)(kb + lq * 128 + (((2 + hi) ^ mK) * 16));
        bf16x8 kf2 = *(const bf16x8*)(kb + lq * 128 + (((4 + hi) ^ mK) * 16));
        bf16x8 kf3 = *(const bf16x8*)(kb + lq * 128 + (((6 + hi) ^ mK) * 16));
        // V B-frags: [t = h-half][s2 = key-half]; row h = t*32+lq
        const int mV0 = (lq & 3) ^ ((lq & 4) >> 2);
        bf16x8 vf00 = *(const bf16x8*)(vb + (lq     ) * 64 + (((0 + hi) ^ mV0) * 16));
        bf16x8 vf01 = *(const bf16x8*)(vb + (lq     ) * 64 + (((2 + hi) ^ mV0) * 16));
        bf16x8 vf10 = *(const bf16x8*)(vb + (lq + 32) * 64 + (((0 + hi) ^ mV0) * 16));
        bf16x8 vf11 = *(const bf16x8*)(vb + (lq + 32) * 64 + (((2 + hi) ^ mV0) * 16));

        // drain frag reads, then refill this buffer with tile kt+8
        WAIT_LGKM0();
        if (kt + 8 <= ktm) stage_kv(k0 + 256, kb);

        // ---- S^T = K Q^T : [32 keys x 32 q] ----
        floatx16 st;
#pragma unroll
        for (int i = 0; i < 16; i++) st[i] = 0.f;
        st = __builtin_amdgcn_mfma_f32_32x32x16_bf16(kf0, qf0, st, 0, 0, 0);
        st = __builtin_amdgcn_mfma_f32_32x32x16_bf16(kf1, qf1, st, 0, 0, 0);
        st = __builtin_amdgcn_mfma_f32_32x32x16_bf16(kf2, qf2, st, 0, 0, 0);
        st = __builtin_amdgcn_mfma_f32_32x32x16_bf16(kf3, qf3, st, 0, 0, 0);

        // ---- mask (diag tile only) + exp2; C row=key=(r&3)+8*(r>>2)+4*hi,
        //      col=q=lq ----
        float p[16];
        if (kt < qt) {
#pragma unroll
            for (int r = 0; r < 16; r++) p[r] = exp2f(st[r]);
        } else {
#pragma unroll
            for (int r = 0; r < 16; r++) {
                const int row = (r & 3) + 8 * (r >> 2) + 4 * hi;
                p[r] = (row <= lq) ? exp2f(st[r]) : 0.f;   // k0==q0 on diag
            }
        }
#pragma unroll
        for (int r = 0; r < 16; r++) ls += p[r];

        // ---- pack P^T -> LDS image P[q][key] as 4x b64 (4 consec keys) ----
#pragma unroll
        for (int g = 0; g < 4; g++) {
            bf16x4 w;
            w[0] = f2bf(p[g * 4 + 0]); w[1] = f2bf(p[g * 4 + 1]);
            w[2] = f2bf(p[g * 4 + 2]); w[3] = f2bf(p[g * 4 + 3]);
            const int sub = g * 2 + hi;              // keys (8g+4hi)..+3
            *(bf16x4*)(Pimg + lq * 64 + ((sub ^ m8) * 8)) = w;
        }

        // ---- PV: A=P[32q x 16k], B=V; O tiles t=0,1 over h halves ----
#pragma unroll
        for (int s2 = 0; s2 < 2; s2++) {
            const int sub0 = s2 * 4 + hi * 2;
            bf16x4 a0 = *(const bf16x4*)(Pimg + lq * 64 + (((sub0    ) ^ m8) * 8));
            bf16x4 a1 = *(const bf16x4*)(Pimg + lq * 64 + (((sub0 + 1) ^ m8) * 8));
            bf16x8 pf;
            pf[0] = a0[0]; pf[1] = a0[1]; pf[2] = a0[2]; pf[3] = a0[3];
            pf[4] = a1[0]; pf[5] = a1[1]; pf[6] = a1[2]; pf[7] = a1[3];
            o0 = __builtin_amdgcn_mfma_f32_32x32x16_bf16(pf, (s2 ? vf01 : vf00), o0, 0, 0, 0);
            o1 = __builtin_amdgcn_mfma_f32_32x32x16_bf16(pf, (s2 ? vf11 : vf10), o1, 0, 0, 0);
        }
    }

    // ---- merge 4-way k-split partials ----
    float lst = ls + __shfl_xor(ls, 32, 64);   // full key-sum for q=lq
    __syncthreads();                           // staging dead from here
    if (hi == 0) Ll[wave * 32 + lq] = lst;
    if (wave != 0) {
        float* Ow = Ol + (wave - 1) * 2048;
#pragma unroll
        for (int r = 0; r < 16; r++) {
            const int q = (r & 3) + 8 * (r >> 2) + 4 * hi;
            Ow[q * 64 + lq]      = o0[r];
            Ow[q * 64 + 32 + lq] = o1[r];
        }
    }
    __syncthreads();
    if (wave == 0) {
#pragma unroll
        for (int r = 0; r < 16; r++) {
            const int q = (r & 3) + 8 * (r >> 2) + 4 * hi;
            const float l4 = Ll[q] + Ll[32 + q] + Ll[64 + q] + Ll[96 + q];
            const float inv = 1.0f / l4;
            float v0 = o0[r] + Ol[q * 64 + lq]
                     + Ol[2048 + q * 64 + lq] + Ol[4096 + q * 64 + lq];
            float v1 = o1[r] + Ol[q * 64 + 32 + lq]
                     + Ol[2048 + q * 64 + 32 + lq] + Ol[4096 + q * 64 + 32 + lq];
            const size_t base = ((size_t)b * N_ + q0 + q) * H_;
            Out[base + lq]      = v0 * inv;
            Out[base + 32 + lq] = v1 * inv;
        }
    }
}

// ---------------------------------------------------------------------------
extern "C" void kernel_launch(void* const* d_in, const int* in_sizes, int n_in,
                              void* d_out, int out_size, void* d_ws, size_t ws_size,
                              hipStream_t stream) {
    const float* X  = (const float*)d_in[0];
    const float* Wq = (const float*)d_in[1];
    const float* Wk = (const float*)d_in[2];
    const float* Wv = (const float*)d_in[3];
    float* Out = (float*)d_out;

    char* ws = (char*)d_ws;
    bf16_t* Qb = (bf16_t*)(ws);
    bf16_t* Kb = (bf16_t*)(ws + (size_t)(2u << 20));
    bf16_t* Vt = (bf16_t*)(ws + (size_t)(4u << 20));
    bf16_t* Wt = (bf16_t*)(ws + (size_t)(6u << 20));

    hipLaunchKernelGGL(wt_kernel, dim3(768, 3), dim3(64), 0, stream, Wq, Wk, Wv, Wt);
    hipLaunchKernelGGL(proj_kernel, dim3(512), dim3(256), 0, stream, X, Wt, Qb, Kb, Vt);
    hipLaunchKernelGGL(attn_kernel, dim3(32, 8, 2), dim3(256), 0, stream, Qb, Kb, Vt, Out);
}

// Round 9
// 120.595 us; speedup vs baseline: 3.9187x; 1.0029x over previous
//
#include <hip/hip_runtime.h>
#include <stdint.h>

typedef __bf16 bf16_t;
typedef __bf16 bf16x8 __attribute__((ext_vector_type(8)));
typedef float floatx4 __attribute__((ext_vector_type(4)));
typedef float floatx16 __attribute__((ext_vector_type(16)));

#define B_ 8
#define N_ 2048
#define D_ 768
#define H_ 64

// raw s_waitcnt imms (gfx9): vm[3:0]=bits3:0, lgkm=bits11:8
#define WAIT_VM0()   { __builtin_amdgcn_sched_barrier(0); __builtin_amdgcn_s_waitcnt(0x0F70); __builtin_amdgcn_sched_barrier(0); }
#define WAIT_LGKM0() { __builtin_amdgcn_sched_barrier(0); __builtin_amdgcn_s_waitcnt(0xC07F); __builtin_amdgcn_sched_barrier(0); }

__device__ __forceinline__ bf16_t f2bf(float f) {
    union { float f; uint32_t u; } v; v.f = f;
    uint32_t u = v.u;
    uint32_t r = (u + 0x7fffu + ((u >> 16) & 1u)) >> 16;
    union { unsigned short s; bf16_t b; } o; o.s = (unsigned short)r;
    return o.b;
}

__device__ __forceinline__ uint32_t pkbf(float lo, float hi_) {
    union { bf16_t b[2]; uint32_t u; } t;
    t.b[0] = f2bf(lo); t.b[1] = f2bf(hi_);
    return t.u;
}

__device__ __forceinline__ void async_cp16(void* l, const void* g) {
    __builtin_amdgcn_global_load_lds(
        (const __attribute__((address_space(1))) uint32_t*)g,
        (__attribute__((address_space(3))) uint32_t*)l, 16, 0, 0);
}

// ---------------------------------------------------------------------------
// Kernel 1: W transpose + cast (unchanged).
// ---------------------------------------------------------------------------
__global__ void wt_kernel(const float* __restrict__ Wq,
                          const float* __restrict__ Wk,
                          const float* __restrict__ Wv,
                          bf16_t* __restrict__ Wt) {
    const int h = threadIdx.x;
    const int k = blockIdx.x;
    const int s = blockIdx.y;
    const float* W = (s == 0) ? Wq : (s == 1) ? Wk : Wv;
    float v = W[k * H_ + h];
    if (s == 0) v *= 0.125f * 1.4426950408889634f;
    Wt[(size_t)(s * 64 + h) * D_ + k] = f2bf(v);
}

// ---------------------------------------------------------------------------
// Kernel 2 (R9): fused QKV projection, N-split for occupancy.
// 1024 blocks: (512 M-tiles of 32 rows) x (2 N-halves of 96 cols).
// LDS 40KB -> 4 blocks/CU resident: barrier drains overlap across blocks
// (R5 showed proj is latency-bound in its one-round 2-block config).
// ---------------------------------------------------------------------------
__launch_bounds__(256, 4)
__global__ void proj_kernel(const float* __restrict__ X,
                            const bf16_t* __restrict__ Wt,
                            bf16_t* __restrict__ Qb,
                            bf16_t* __restrict__ Kb,
                            bf16_t* __restrict__ Vt) {
    const int wave = threadIdx.x >> 6;
    const int lane = threadIdx.x & 63;
    const int quad = lane >> 4;
    const int l16  = lane & 15;
    const int rowhalf = wave & 1;
    const int colhalf = wave >> 1;                  // 0/1 -> 48-col half
    const int nb = blockIdx.x & 1;                  // N-half
    const int colbase = nb * 96;
    const int m0blk = (blockIdx.x >> 1) * 32;

    __shared__ __align__(16) float  As[2][32 * 64];
    __shared__ __align__(16) bf16_t Bs[2][96 * 64];

    floatx4 acc[3];
#pragma unroll
    for (int i = 0; i < 3; i++) acc[i] = (floatx4){0.f, 0.f, 0.f, 0.f};

    auto stage = [&](int buf, int k0) {
#pragma unroll
        for (int i = 0; i < 2; i++) {
            const int r = (wave * 2 + i) * 4 + (lane >> 4);        // 0..31
            const int c = (lane & 15) ^ (r & 15);
            const float* g = X + (size_t)(m0blk + r) * D_ + k0 + c * 4;
            async_cp16((char*)&As[buf][0] + (wave * 2 + i) * 1024, g);
        }
#pragma unroll
        for (int i = 0; i < 3; i++) {
            const int r = (wave * 3 + i) * 8 + (lane >> 3);        // 0..95
            const int c = (lane & 7) ^ (r & 7);
            const bf16_t* g = Wt + (size_t)(colbase + r) * D_ + k0 + c * 8;
            async_cp16((char*)&Bs[buf][0] + (wave * 3 + i) * 1024, g);
        }
    };

    const int arow = rowhalf * 16 + l16;

    stage(0, 0);
    for (int ch = 0; ch < 12; ch++) {
        __syncthreads();
        if (ch + 1 < 12) stage((ch + 1) & 1, (ch + 1) * 64);

        const char* Ab = (const char*)&As[ch & 1][0];
        const char* Bb = (const char*)&Bs[ch & 1][0];
#pragma unroll
        for (int kh = 0; kh < 2; kh++) {
            const int c0 = kh * 8 + quad * 2;
            float4 xa = *(const float4*)(Ab + arow * 256 + ((c0 ^ l16) & 15) * 16);
            float4 xb = *(const float4*)(Ab + arow * 256 + (((c0 + 1) ^ l16) & 15) * 16);
            bf16x8 af;
            af[0] = f2bf(xa.x); af[1] = f2bf(xa.y);
            af[2] = f2bf(xa.z); af[3] = f2bf(xa.w);
            af[4] = f2bf(xb.x); af[5] = f2bf(xb.y);
            af[6] = f2bf(xb.z); af[7] = f2bf(xb.w);
            const int cb = kh * 4 + quad;
#pragma unroll
            for (int nt = 0; nt < 3; nt++) {
                const int nl = colhalf * 48 + nt * 16 + l16;       // 0..95
                bf16x8 bf = *(const bf16x8*)(Bb + nl * 128 + ((cb ^ (nl & 7))) * 16);
                acc[nt] = __builtin_amdgcn_mfma_f32_16x16x32_bf16(af, bf, acc[nt], 0, 0, 0);
            }
        }
    }

#pragma unroll
    for (int nt = 0; nt < 3; nt++) {
        const int c = colbase + colhalf * 48 + nt * 16 + l16;      // 0..191
#pragma unroll
        for (int r = 0; r < 4; r++) {
            const int m = m0blk + rowhalf * 16 + quad * 4 + r;
            bf16_t val = f2bf(acc[nt][r]);
            if (c < 64) {
                Qb[(size_t)m * H_ + c] = val;
            } else if (c < 128) {
                Kb[(size_t)m * H_ + (c - 64)] = val;
            } else {
                const int b = m >> 11, n = m & 2047, h = c - 128;
                Vt[((size_t)b * H_ + h) * N_ + n] = val;
            }
        }
    }
}

// ---------------------------------------------------------------------------
// Kernel 3 (R9): flash attention, 32x32x16 MFMA, 512-thread blocks.
// 8 waves = 8-way wave-private k-split -> 16 waves/CU (2x R8 overlap).
// K DMA-staged depth-2 (4KB/tile/wave); V read DIRECT from global (Vt is
// L2-resident; latency hidden under S+exp2 by 4 waves/SIMD).  P C->A
// transform done IN REGISTERS via 4x shfl_xor(32) packed-pair exchange
// (no LDS round-trip).  Wait scheme: first-iter vmcnt(0) drain; afterwards
// the compiler's own V-load waits (V pinned before the refill DMA) force
// vmcnt<=4, transitively draining each buffer's DMA one iter ahead.
// Parallel float4 merge epilogue over all 512 threads.
// ---------------------------------------------------------------------------
__launch_bounds__(512, 4)
__global__ void attn_kernel(const bf16_t* __restrict__ Qb,
                            const bf16_t* __restrict__ Kb,
                            const bf16_t* __restrict__ Vt,
                            float* __restrict__ Out) {
    const int x = blockIdx.x;            // 0..31
    const int b = blockIdx.y;            // 0..7
    const int z = blockIdx.z;            // 0..1
    const int qt = z ? (63 - x) : x;
    const int q0 = qt * 32;

    const int tid  = threadIdx.x;
    const int wave = tid >> 6;           // k-split 0..7
    const int lane = tid & 63;
    const int hi   = lane >> 5;
    const int lq   = lane & 31;

    // LDS: K staging 8 waves x 2 bufs x 4KB = 64KB; Ll 1KB after.
    // Ol[8][32][64] fp32 (64KB) aliases staging (used after __syncthreads).
    __shared__ __align__(16) char smem[8 * 8192 + 1024];
    char* mybase = smem + wave * 8192;
    float* Ol = (float*)smem;            // [8][32][64]
    float* Ll = (float*)(smem + 65536);  // [8][32]

    const bf16_t* KpB = Kb + (size_t)b * N_ * H_;
    const bf16_t* VpB = Vt + (size_t)b * H_ * N_;

    // Q B-frags: B[k=h][n=q], n=lq, k = s*16 + hi*8 + j
    const bf16_t* qrow = Qb + ((size_t)b * N_ + q0 + lq) * H_ + hi * 8;
    bf16x8 qf0 = *(const bf16x8*)(qrow);
    bf16x8 qf1 = *(const bf16x8*)(qrow + 16);
    bf16x8 qf2 = *(const bf16x8*)(qrow + 32);
    bf16x8 qf3 = *(const bf16x8*)(qrow + 48);

    floatx16 o0, o1;
#pragma unroll
    for (int i = 0; i < 16; i++) { o0[i] = 0.f; o1[i] = 0.f; }
    float ls = 0.f;

    // K DMA: 32 rows x 8 cells(16B); logical cell c at phys c^((r&7)^((r&8)>>1))
    const int rK = lane >> 3, cK = lane & 7;
    auto stage_k = [&](int k0, char* buf) {
#pragma unroll
        for (int i = 0; i < 4; i++) {
            const int r = i * 8 + rK;
            const int mk = rK ^ ((i & 1) << 2);
            async_cp16(buf + i * 1024,
                       KpB + (size_t)(k0 + r) * H_ + (cK ^ mk) * 8);
        }
    };

    const int ktm = qt;                  // inclusive max k-tile
    if (wave <= ktm)     stage_k(wave * 32, mybase);
    if (wave + 8 <= ktm) stage_k((wave + 8) * 32, mybase + 4096);

    const int mK = (lq & 7) ^ ((lq & 8) >> 1);

    for (int kt = wave; kt <= ktm; kt += 8) {
        const int k0 = kt * 32;
        char* kb = mybase + (((kt - wave) >> 3) & 1) * 4096;

        if (kt == wave) { WAIT_VM0(); }  // first iter: buffer fully landed

        // ---- K A-frags from staged LDS (conflict-free) ----
        bf16x8 kf0 = *(const bf16x8*)(kb + lq * 128 + (((0 + hi) ^ mK) * 16));
        bf16x8 kf1 = *(const bf16x8*)(kb + lq * 128 + (((2 + hi) ^ mK) * 16));
        bf16x8 kf2 = *(const bf16x8*)(kb + lq * 128 + (((4 + hi) ^ mK) * 16));
        bf16x8 kf3 = *(const bf16x8*)(kb + lq * 128 + (((6 + hi) ^ mK) * 16));
        WAIT_LGKM0();                    // reads done before buffer refill

        // ---- V direct loads (BEFORE refill DMA: compiler's V-wait then
        //      leaves the refill in flight while draining older DMAs) ----
        const bf16_t* vrow0 = VpB + (size_t)lq * N_ + k0 + 8 * hi;
        const bf16_t* vrow1 = vrow0 + (size_t)32 * N_;
        bf16x8 vf00 = *(const bf16x8*)(vrow0);        // t=0, s=0
        bf16x8 vf01 = *(const bf16x8*)(vrow0 + 16);   // t=0, s=1
        bf16x8 vf10 = *(const bf16x8*)(vrow1);        // t=1, s=0
        bf16x8 vf11 = *(const bf16x8*)(vrow1 + 16);   // t=1, s=1
        __builtin_amdgcn_sched_barrier(0);
        if (kt + 16 <= ktm) stage_k(k0 + 512, kb);

        // ---- S^T = K Q^T : [32 keys x 32 q] ----
        floatx16 st;
#pragma unroll
        for (int i = 0; i < 16; i++) st[i] = 0.f;
        st = __builtin_amdgcn_mfma_f32_32x32x16_bf16(kf0, qf0, st, 0, 0, 0);
        st = __builtin_amdgcn_mfma_f32_32x32x16_bf16(kf1, qf1, st, 0, 0, 0);
        st = __builtin_amdgcn_mfma_f32_32x32x16_bf16(kf2, qf2, st, 0, 0, 0);
        st = __builtin_amdgcn_mfma_f32_32x32x16_bf16(kf3, qf3, st, 0, 0, 0);

        // ---- mask (diag tile only) + exp2, in place ----
        if (kt < qt) {
#pragma unroll
            for (int r = 0; r < 16; r++) st[r] = exp2f(st[r]);
        } else {
#pragma unroll
            for (int r = 0; r < 16; r++) {
                const int row = (r & 3) + 8 * (r >> 2) + 4 * hi;   // key
                st[r] = (row <= lq) ? exp2f(st[r]) : 0.f;
            }
        }
#pragma unroll
        for (int r = 0; r < 16; r++) ls += st[r];

        // ---- P C->A in registers: packed-pair exchange across hi halves.
        // pair t: (st[2t], st[2t+1]) = keys {2(t&1) + 8*(t>>1) + 4hi, +1}.
        uint32_t pb[8];
#pragma unroll
        for (int t = 0; t < 8; t++) pb[t] = pkbf(st[2 * t], st[2 * t + 1]);
        uint32_t rc[4];
#pragma unroll
        for (int t = 0; t < 4; t++) {
            const uint32_t w = hi ? pb[(t & 1) + 4 * (t >> 1)]
                                  : pb[(t & 1) + 2 + 4 * (t >> 1)];
            rc[t] = (uint32_t)__shfl_xor((int)w, 32, 64);
        }
        union { uint32_t u[4]; bf16x8 v; } f0, f1;
        f0.u[0] = hi ? rc[0] : pb[0]; f0.u[1] = hi ? rc[1] : pb[1];
        f0.u[2] = hi ? pb[2] : rc[0]; f0.u[3] = hi ? pb[3] : rc[1];
        f1.u[0] = hi ? rc[2] : pb[4]; f1.u[1] = hi ? rc[3] : pb[5];
        f1.u[2] = hi ? pb[6] : rc[2]; f1.u[3] = hi ? pb[7] : rc[3];

        // ---- PV ----
        o0 = __builtin_amdgcn_mfma_f32_32x32x16_bf16(f0.v, vf00, o0, 0, 0, 0);
        o0 = __builtin_amdgcn_mfma_f32_32x32x16_bf16(f1.v, vf01, o0, 0, 0, 0);
        o1 = __builtin_amdgcn_mfma_f32_32x32x16_bf16(f0.v, vf10, o1, 0, 0, 0);
        o1 = __builtin_amdgcn_mfma_f32_32x32x16_bf16(f1.v, vf11, o1, 0, 0, 0);
    }

    // ---- merge 8-way k-split: all waves dump partials, parallel reduce ----
    float lst = ls + __shfl_xor(ls, 32, 64);
    __syncthreads();                     // staging region dead from here
    if (hi == 0) Ll[wave * 32 + lq] = lst;
#pragma unroll
    for (int r = 0; r < 16; r++) {
        const int q = (r & 3) + 8 * (r >> 2) + 4 * hi;
        Ol[((size_t)wave * 32 + q) * 64 + lq]      = o0[r];
        Ol[((size_t)wave * 32 + q) * 64 + 32 + lq] = o1[r];
    }
    __syncthreads();
    {
        const int q  = tid >> 4;         // 0..31
        const int h4 = (tid & 15) * 4;   // 0..60
        floatx4 a = (floatx4){0.f, 0.f, 0.f, 0.f};
        float l = 0.f;
#pragma unroll
        for (int w = 0; w < 8; w++) {
            const floatx4 part = *(const floatx4*)&Ol[((size_t)w * 32 + q) * 64 + h4];
            a += part;
            l += Ll[w * 32 + q];
        }
        const float inv = 1.0f / l;
        float4 outv = {a[0] * inv, a[1] * inv, a[2] * inv, a[3] * inv};
        *(float4*)&Out[((size_t)b * N_ + q0 + q) * H_ + h4] = outv;
    }
}

// ---------------------------------------------------------------------------
extern "C" void kernel_launch(void* const* d_in, const int* in_sizes, int n_in,
                              void* d_out, int out_size, void* d_ws, size_t ws_size,
                              hipStream_t stream) {
    const float* X  = (const float*)d_in[0];
    const float* Wq = (const float*)d_in[1];
    const float* Wk = (const float*)d_in[2];
    const float* Wv = (const float*)d_in[3];
    float* Out = (float*)d_out;

    char* ws = (char*)d_ws;
    bf16_t* Qb = (bf16_t*)(ws);
    bf16_t* Kb = (bf16_t*)(ws + (size_t)(2u << 20));
    bf16_t* Vt = (bf16_t*)(ws + (size_t)(4u << 20));
    bf16_t* Wt = (bf16_t*)(ws + (size_t)(6u << 20));

    hipLaunchKernelGGL(wt_kernel, dim3(768, 3), dim3(64), 0, stream, Wq, Wk, Wv, Wt);
    hipLaunchKernelGGL(proj_kernel, dim3(1024), dim3(256), 0, stream, X, Wt, Qb, Kb, Vt);
    hipLaunchKernelGGL(attn_kernel, dim3(32, 8, 2), dim3(512), 0, stream, Qb, Kb, Vt, Out);
}